// Round 4
// baseline (9458.812 us; speedup 1.0000x reference)
//
#include <hip/hip_runtime.h>
#include <stdint.h>
#include <stddef.h>

#define VOCAB  128
#define HIDDEN 1024
#define BATCH  64
#define SEQ    512

#define NGROUP 4      // batch groups
#define BG     16     // batches per group
#define NWG    16     // workgroups per group (column slices)
#define CJ     64     // W_hh columns per WG
#define NVW    8      // vocab rows per WG
#define NTHR   512

// ws layout in float units
#define E2_OFF   0          // [128][1024] f32
#define WOT_OFF  131072     // [128][1024] f32
#define HP_OFF   262144     // [2][64][1024] f32 ping-pong h
#define FLG_OFF  393216     // flags: (g*16+w) at stride 16 ints (64B)

typedef __attribute__((ext_vector_type(8))) short short8_t;
typedef __attribute__((ext_vector_type(4))) float f32x4;

// ---------------- coherent (cross-XCD, MALL-level) access helpers ----------------
__device__ __forceinline__ float4 cload4(const float* p) {
    float4 v;
    asm volatile("global_load_dwordx4 %0, %1, off sc0 sc1" : "=v"(v) : "v"(p));
    return v;
}
__device__ __forceinline__ int cloadi(const int* p) {
    int v;
    asm volatile("global_load_dword %0, %1, off sc0 sc1\n\ts_waitcnt vmcnt(0)"
                 : "=v"(v) : "v"(p) : "memory");
    return v;
}
__device__ __forceinline__ void cstoref(float* p, float x) {
    asm volatile("global_store_dword %0, %1, off sc0 sc1" :: "v"(p), "v"(x) : "memory");
}
__device__ __forceinline__ void cstorei(int* p, int x) {
    asm volatile("global_store_dword %0, %1, off sc0 sc1" :: "v"(p), "v"(x) : "memory");
}
#define WAITVM0() asm volatile("s_waitcnt vmcnt(0)" ::: "memory")

// ---------------- bf16 split helpers ----------------
__device__ __forceinline__ unsigned short bf16_rne(float f) {
    unsigned int u = __float_as_uint(f);
    u += 0x7FFF + ((u >> 16) & 1);
    return (unsigned short)(u >> 16);
}
__device__ __forceinline__ float bf16_f32(unsigned short h) {
    return __uint_as_float(((unsigned int)h) << 16);
}
__device__ __forceinline__ void split8(const float4 a, const float4 b,
                                       short8_t* h8, short8_t* l8) {
    float f0=a.x,f1=a.y,f2=a.z,f3=a.w,f4=b.x,f5=b.y,f6=b.z,f7=b.w;
    unsigned short h;
    h=bf16_rne(f0); (*h8)[0]=(short)h; (*l8)[0]=(short)bf16_rne(f0-bf16_f32(h));
    h=bf16_rne(f1); (*h8)[1]=(short)h; (*l8)[1]=(short)bf16_rne(f1-bf16_f32(h));
    h=bf16_rne(f2); (*h8)[2]=(short)h; (*l8)[2]=(short)bf16_rne(f2-bf16_f32(h));
    h=bf16_rne(f3); (*h8)[3]=(short)h; (*l8)[3]=(short)bf16_rne(f3-bf16_f32(h));
    h=bf16_rne(f4); (*h8)[4]=(short)h; (*l8)[4]=(short)bf16_rne(f4-bf16_f32(h));
    h=bf16_rne(f5); (*h8)[5]=(short)h; (*l8)[5]=(short)bf16_rne(f5-bf16_f32(h));
    h=bf16_rne(f6); (*h8)[6]=(short)h; (*l8)[6]=(short)bf16_rne(f6-bf16_f32(h));
    h=bf16_rne(f7); (*h8)[7]=(short)h; (*l8)[7]=(short)bf16_rne(f7-bf16_f32(h));
}

// ---------------- E2 = emb @ W_hx + b_hx ----------------
__global__ void e2_kernel(const float* __restrict__ emb, const float* __restrict__ W_hx,
                          const float* __restrict__ b_hx, float* __restrict__ E2) {
    int v = blockIdx.x >> 2;
    int j = (blockIdx.x & 3) * 256 + threadIdx.x;
    const float* er = emb + (size_t)v * HIDDEN;
    float acc = 0.f;
#pragma unroll 8
    for (int k = 0; k < HIDDEN; ++k)
        acc += er[k] * W_hx[(size_t)k * HIDDEN + j];
    E2[(size_t)v * HIDDEN + j] = acc + b_hx[j];
}

// ---------------- WoT[v][k] = W_out[k][v] ----------------
__global__ void wot_kernel(const float* __restrict__ W_out, float* __restrict__ WoT) {
    int v  = blockIdx.x;
    int k4 = threadIdx.x;
    float4 r;
    r.x = W_out[(size_t)(k4*4+0)*VOCAB + v];
    r.y = W_out[(size_t)(k4*4+1)*VOCAB + v];
    r.z = W_out[(size_t)(k4*4+2)*VOCAB + v];
    r.w = W_out[(size_t)(k4*4+3)*VOCAB + v];
    ((float4*)(WoT + (size_t)v * HIDDEN))[k4] = r;
}

// ---------------- all-wave group barrier poll ----------------
__device__ __forceinline__ void group_poll(const int* flags, int g, int lane, int target) {
    const int* fp = flags + (((size_t)g * 16 + (lane & 15)) << 4);
    int guard = 0;
    for (;;) {
        int v = target;
        if (lane < 16) v = cloadi(fp);
        if (__all(v >= target)) break;
        if (++guard > (1 << 22)) break;
        __builtin_amdgcn_s_sleep(1);
    }
}

// ---------------- persistent recurrence kernel ----------------
// grid = 64 blocks (4 groups x 16 col-slices of 64), 512 threads (8 waves), 132KB LDS.
// waves: wv = ct(4) x ks(2): column-tile ct (16 cols), k-slice ks (512 k).
// LDS: sHi/sLo double-buffered [16][1024] bf16 chunk-swizzled; sPart[4][16][16] f32.
extern "C" __global__ void __launch_bounds__(NTHR, 2)
rnn_kernel(const int* __restrict__ x, const float* __restrict__ h0,
           const float* __restrict__ W_hh,
           const float* __restrict__ E2, const float* __restrict__ WoT,
           const float* __restrict__ b_out,
           float* __restrict__ hp, int* __restrict__ flags,
           float* __restrict__ logits, float* __restrict__ hf) {
    extern __shared__ char lds_raw[];
    // buffers: p*65536 bytes each {sHi 32KB, sLo 32KB}; sPart at 128KB
    float* sPart = (float*)(lds_raw + 131072);      // 4*16*16 f32 = 4KB

    const int bid = blockIdx.x;
    const int g  = bid & 3;
    const int w  = bid >> 2;
    const int b0 = g * BG;
    const int j0 = w * CJ;
    const int tid  = threadIdx.x;
    const int lane = tid & 63;
    const int wv   = tid >> 6;
    const int ct   = wv & 3;
    const int ks   = wv >> 2;
    const int ar   = lane & 15;       // A row / C col
    const int acg  = lane >> 4;       // k-subgroup / C row-group

    // ---- prologue: W_hh slice -> bf16 hi/lo fragments in VGPRs ----
    // wave (ct,ks): B[k = ks*512 + kc*32 + acg*8 + e][col = j0 + ct*16 + ar]
    short8_t whi[16], wlo[16];
    {
        const int col = j0 + ct * 16 + ar;
#pragma unroll
        for (int kc = 0; kc < 16; ++kc) {
            int kb = ks * 512 + kc * 32 + acg * 8;
#pragma unroll
            for (int e = 0; e < 8; ++e) {
                float wval = W_hh[(size_t)(kb + e) * HIDDEN + col];
                unsigned short hi = bf16_rne(wval);
                whi[kc][e] = (short)hi;
                wlo[kc][e] = (short)bf16_rne(wval - bf16_f32(hi));
            }
        }
    }

    // logits mapping: b=tid>>5, v2=(tid&31)>>2, kz=tid&3
    const int lb = tid >> 5;
    const int v2 = (tid & 31) >> 2;
    const int kz = tid & 3;
    const float bo = b_out[w * NVW + v2];
    const float* wrow = WoT + (size_t)(w * NVW + v2) * HIDDEN + kz * 256;

    const int srow = tid >> 5, sslt = tid & 31;

    for (int t = 0; t < SEQ; ++t) {
        if (t > 0) group_poll(flags, g, lane, t);

        const int p = t & 1;
        short* sHi_p = (short*)(lds_raw + p * 65536);
        short* sLo_p = sHi_p + 16 * 1024;

        // ---- stage h_t (f32) -> bf16 hi/lo LDS buf p; chunk c stored at c^(srow&7) ----
        {
            const float* src = (t == 0) ? (h0 + (size_t)b0 * HIDDEN)
                                        : (hp + (size_t)((t - 1) & 1) * BATCH * HIDDEN
                                              + (size_t)b0 * HIDDEN);
            float4 f[8];
#pragma unroll
            for (int i = 0; i < 4; ++i) {
                int c = i * 32 + sslt;
                const float* q = src + (size_t)srow * HIDDEN + c * 8;
                f[2*i]   = cload4(q);
                f[2*i+1] = cload4(q + 4);
            }
            WAITVM0();
            __builtin_amdgcn_sched_barrier(0);
#pragma unroll
            for (int i = 0; i < 4; ++i) {
                int c = i * 32 + sslt;
                int cs = (c ^ (srow & 7)) << 3;
                short8_t h8, l8;
                split8(f[2*i], f[2*i+1], &h8, &l8);
                *(short8_t*)(sHi_p + srow * 1024 + cs) = h8;
                *(short8_t*)(sLo_p + srow * 1024 + cs) = l8;
            }
        }
        // e2 prefetch for finish phase (ks==0 waves only)
        float e2v[4];
        if (ks == 0) {
#pragma unroll
            for (int q = 0; q < 4; ++q) {
                int b = acg * 4 + q;
                int xv = x[(size_t)(b0 + b) * SEQ + t];
                e2v[q] = E2[(size_t)xv * HIDDEN + j0 + ct * 16 + ar];
            }
        }
        __syncthreads();   // (a)

        // ---- MFMA: C[16b x 16j(ct)] over k-slice ks; 4 independent sub-chains ----
        f32x4 acc[4];
#pragma unroll
        for (int i = 0; i < 4; ++i) acc[i] = (f32x4){0.f, 0.f, 0.f, 0.f};
#pragma unroll
        for (int kc = 0; kc < 16; ++kc) {
            int c8 = ks * 64 + kc * 4 + acg;
            int off = ar * 1024 + ((c8 ^ (ar & 7)) << 3);
            short8_t ahi = *(const short8_t*)(sHi_p + off);
            short8_t alo = *(const short8_t*)(sLo_p + off);
            int ai = kc & 3;
            acc[ai] = __builtin_amdgcn_mfma_f32_16x16x32_bf16(ahi, whi[kc], acc[ai], 0, 0, 0);
            acc[ai] = __builtin_amdgcn_mfma_f32_16x16x32_bf16(alo, whi[kc], acc[ai], 0, 0, 0);
            acc[ai] = __builtin_amdgcn_mfma_f32_16x16x32_bf16(ahi, wlo[kc], acc[ai], 0, 0, 0);
        }
        f32x4 aS;
#pragma unroll
        for (int q = 0; q < 4; ++q) aS[q] = acc[0][q] + acc[1][q] + acc[2][q] + acc[3][q];

        if (ks == 1) {
#pragma unroll
            for (int q = 0; q < 4; ++q)
                sPart[ct * 256 + (acg * 4 + q) * 16 + ar] = aS[q];
        }
        __syncthreads();   // (b)

        if (ks == 0) {
            float* hpo = hp + (size_t)(t & 1) * BATCH * HIDDEN;
#pragma unroll
            for (int q = 0; q < 4; ++q) {
                int b = acg * 4 + q;
                float s = aS[q] + sPart[ct * 256 + b * 16 + ar] + e2v[q];
                float hn = tanhf(s);
                cstoref(hpo + (size_t)(b0 + b) * HIDDEN + j0 + ct * 16 + ar, hn);
                if (t == SEQ - 1)
                    hf[(size_t)(b0 + b) * HIDDEN + j0 + ct * 16 + ar] = hn;
            }
            WAITVM0();
        }
        __syncthreads();   // (c): all h stores acked
        if (tid == 0)
            cstorei(flags + (((size_t)g * 16 + w) << 4), t + 1);

        // ---- fused logits for position t-1 (h-hi only), overlaps peers' next step ----
        if (t > 0) {
            const short* hRow = sHi_p + lb * 1024;
            const int bx = lb & 7;
            float a = 0.f;
#pragma unroll 8
            for (int m = 0; m < 32; ++m) {
                int c = kz * 32 + m;
                short8_t h8 = *(const short8_t*)(hRow + ((c ^ bx) << 3));
                float4 wa = *(const float4*)(wrow + m * 8);
                float4 wb = *(const float4*)(wrow + m * 8 + 4);
                a += bf16_f32((unsigned short)h8[0]) * wa.x;
                a += bf16_f32((unsigned short)h8[1]) * wa.y;
                a += bf16_f32((unsigned short)h8[2]) * wa.z;
                a += bf16_f32((unsigned short)h8[3]) * wa.w;
                a += bf16_f32((unsigned short)h8[4]) * wb.x;
                a += bf16_f32((unsigned short)h8[5]) * wb.y;
                a += bf16_f32((unsigned short)h8[6]) * wb.z;
                a += bf16_f32((unsigned short)h8[7]) * wb.w;
            }
            a += __shfl_xor(a, 1);
            a += __shfl_xor(a, 2);
            if (kz == 0)
                logits[((size_t)(b0 + lb) * SEQ + (t - 1)) * VOCAB + w * NVW + v2] = a + bo;
        }
    }

    // ---- epilogue: logits for position SEQ-1 from h_SEQ ----
    group_poll(flags, g, lane, SEQ);
    short* sHi_p = (short*)(lds_raw);        // buf 0
    short* sLo_p = sHi_p + 16 * 1024;
    {
        const float* src = hp + (size_t)((SEQ - 1) & 1) * BATCH * HIDDEN + (size_t)b0 * HIDDEN;
        float4 f[8];
#pragma unroll
        for (int i = 0; i < 4; ++i) {
            int c = i * 32 + sslt;
            const float* q = src + (size_t)srow * HIDDEN + c * 8;
            f[2*i]   = cload4(q);
            f[2*i+1] = cload4(q + 4);
        }
        WAITVM0();
        __builtin_amdgcn_sched_barrier(0);
#pragma unroll
        for (int i = 0; i < 4; ++i) {
            int c = i * 32 + sslt;
            int cs = (c ^ (srow & 7)) << 3;
            short8_t h8, l8;
            split8(f[2*i], f[2*i+1], &h8, &l8);
            *(short8_t*)(sHi_p + srow * 1024 + cs) = h8;
            *(short8_t*)(sLo_p + srow * 1024 + cs) = l8;
        }
    }
    __syncthreads();
    {
        const short* hRow = sHi_p + lb * 1024;
        const int bx = lb & 7;
        float a = 0.f;
#pragma unroll 8
        for (int m = 0; m < 32; ++m) {
            int c = kz * 32 + m;
            short8_t h8 = *(const short8_t*)(hRow + ((c ^ bx) << 3));
            float4 wa = *(const float4*)(wrow + m * 8);
            float4 wb = *(const float4*)(wrow + m * 8 + 4);
            a += bf16_f32((unsigned short)h8[0]) * wa.x;
            a += bf16_f32((unsigned short)h8[1]) * wa.y;
            a += bf16_f32((unsigned short)h8[2]) * wa.z;
            a += bf16_f32((unsigned short)h8[3]) * wa.w;
            a += bf16_f32((unsigned short)h8[4]) * wb.x;
            a += bf16_f32((unsigned short)h8[5]) * wb.y;
            a += bf16_f32((unsigned short)h8[6]) * wb.z;
            a += bf16_f32((unsigned short)h8[7]) * wb.w;
        }
        a += __shfl_xor(a, 1);
        a += __shfl_xor(a, 2);
        if (kz == 0)
            logits[((size_t)(b0 + lb) * SEQ + (SEQ - 1)) * VOCAB + w * NVW + v2] = a + bo;
    }
}

extern "C" void kernel_launch(void* const* d_in, const int* in_sizes, int n_in,
                              void* d_out, int out_size, void* d_ws, size_t ws_size,
                              hipStream_t stream) {
    (void)in_sizes; (void)n_in; (void)out_size; (void)ws_size;
    const int*   x     = (const int*)  d_in[0];
    const float* h0    = (const float*)d_in[1];
    const float* emb   = (const float*)d_in[2];
    const float* W_hx  = (const float*)d_in[3];
    const float* b_hx  = (const float*)d_in[4];
    const float* W_hh  = (const float*)d_in[5];
    const float* W_out = (const float*)d_in[6];
    const float* b_out = (const float*)d_in[7];

    float* logits = (float*)d_out;
    float* hf     = logits + (size_t)BATCH * SEQ * VOCAB;

    float* ws  = (float*)d_ws;
    float* E2  = ws + E2_OFF;
    float* WoT = ws + WOT_OFF;
    float* hp  = ws + HP_OFF;
    int*   flags = (int*)(ws + FLG_OFF);

    hipMemsetAsync(flags, 0, NGROUP * 16 * 64, stream);
    e2_kernel<<<512, 256, 0, stream>>>(emb, W_hx, b_hx, E2);
    wot_kernel<<<128, 256, 0, stream>>>(W_out, WoT);

    hipFuncSetAttribute(reinterpret_cast<const void*>(rnn_kernel),
                        hipFuncAttributeMaxDynamicSharedMemorySize, 135168);
    rnn_kernel<<<NGROUP * NWG, NTHR, 135168, stream>>>(x, h0, W_hh, E2, WoT, b_out,
                                                       hp, flags, logits, hf);
}

// Round 5
// 3926.484 us; speedup vs baseline: 2.4090x; 2.4090x over previous
//
#include <hip/hip_runtime.h>
#include <stdint.h>
#include <stddef.h>

#define VOCAB  128
#define HIDDEN 1024
#define BATCH  64
#define SEQ    512

#define NGROUP 4      // batch groups
#define BG     16     // batches per group
#define NWG    16     // workgroups per group (column slices)
#define CJ     64     // W_hh columns per WG
#define NVW    8      // vocab rows per WG
#define NTHR   1024   // 16 waves

// ws layout in float units
#define E2_OFF   0          // [128][1024] f32
#define WOT_OFF  131072     // [128][1024] f32
#define HP_OFF   262144     // [2][64][1024] f32 ping-pong h
#define FLG_OFF  393216     // flags: (g*16+w) at stride 16 ints (64B)

typedef __attribute__((ext_vector_type(8))) short short8_t;
typedef __attribute__((ext_vector_type(4))) float f32x4;

// ---------------- coherent (cross-XCD, MALL-level) access helpers ----------------
__device__ __forceinline__ float4 cload4(const float* p) {
    float4 v;
    asm volatile("global_load_dwordx4 %0, %1, off sc0 sc1" : "=v"(v) : "v"(p));
    return v;
}
__device__ __forceinline__ int cloadi(const int* p) {
    int v;
    asm volatile("global_load_dword %0, %1, off sc0 sc1\n\ts_waitcnt vmcnt(0)"
                 : "=v"(v) : "v"(p) : "memory");
    return v;
}
__device__ __forceinline__ void cstoref(float* p, float x) {
    asm volatile("global_store_dword %0, %1, off sc0 sc1" :: "v"(p), "v"(x) : "memory");
}
__device__ __forceinline__ void cstorei(int* p, int x) {
    asm volatile("global_store_dword %0, %1, off sc0 sc1" :: "v"(p), "v"(x) : "memory");
}
#define WAITVM0() asm volatile("s_waitcnt vmcnt(0)" ::: "memory")

// ---------------- bf16 split helpers ----------------
__device__ __forceinline__ unsigned short bf16_rne(float f) {
    unsigned int u = __float_as_uint(f);
    u += 0x7FFF + ((u >> 16) & 1);
    return (unsigned short)(u >> 16);
}
__device__ __forceinline__ float bf16_f32(unsigned short h) {
    return __uint_as_float(((unsigned int)h) << 16);
}
__device__ __forceinline__ void split8(const float4 a, const float4 b,
                                       short8_t* h8, short8_t* l8) {
    float f[8] = {a.x, a.y, a.z, a.w, b.x, b.y, b.z, b.w};
#pragma unroll
    for (int e = 0; e < 8; ++e) {
        unsigned short hh = bf16_rne(f[e]);
        (*h8)[e] = (short)hh;
        (*l8)[e] = (short)bf16_rne(f[e] - bf16_f32(hh));
    }
}

// ---------------- E2 = emb @ W_hx + b_hx ----------------
__global__ void e2_kernel(const float* __restrict__ emb, const float* __restrict__ W_hx,
                          const float* __restrict__ b_hx, float* __restrict__ E2) {
    int v = blockIdx.x >> 2;
    int j = (blockIdx.x & 3) * 256 + threadIdx.x;
    const float* er = emb + (size_t)v * HIDDEN;
    float acc = 0.f;
#pragma unroll 8
    for (int k = 0; k < HIDDEN; ++k)
        acc += er[k] * W_hx[(size_t)k * HIDDEN + j];
    E2[(size_t)v * HIDDEN + j] = acc + b_hx[j];
}

// ---------------- WoT[v][k] = W_out[k][v] ----------------
__global__ void wot_kernel(const float* __restrict__ W_out, float* __restrict__ WoT) {
    int v  = blockIdx.x;
    int k4 = threadIdx.x;
    float4 r;
    r.x = W_out[(size_t)(k4*4+0)*VOCAB + v];
    r.y = W_out[(size_t)(k4*4+1)*VOCAB + v];
    r.z = W_out[(size_t)(k4*4+2)*VOCAB + v];
    r.w = W_out[(size_t)(k4*4+3)*VOCAB + v];
    ((float4*)(WoT + (size_t)v * HIDDEN))[k4] = r;
}

// ---------------- single-wave group barrier poll (16 flags) ----------------
__device__ __forceinline__ void group_poll(const int* flags, int g, int lane, int target) {
    const int* fp = flags + (((size_t)g * 16 + (lane & 15)) << 4);
    int guard = 0;
    for (;;) {
        int v = target;
        if (lane < 16) v = cloadi(fp);
        if (__all(v >= target)) break;
        if (++guard > (1 << 22)) break;
        __builtin_amdgcn_s_sleep(1);
    }
}

// ---------------- fused logits for one staged h (bf16-hi only) ----------------
// thread map: lb=tid>>6 (batch), v2=(tid>>3)&7 (vocab), kz=tid&7 (k-slice)
__device__ __forceinline__ void logits_phase(const short* sHi, const float* wrowBase,
                                             float bo, float* logits,
                                             int b0, int w, int tprev,
                                             int lb, int v2, int kz) {
    const short* hRow = sHi + lb * 1024;
    const int bx = lb & 7;
    float a = 0.f;
#pragma unroll 4
    for (int m = 0; m < 16; ++m) {
        int c = m * 8 + kz;                          // logical chunk (8 k each)
        short8_t h8 = *(const short8_t*)(hRow + ((c ^ bx) << 3));
        const float* wp = wrowBase + m * 64 + kz * 8;
        float4 wa = *(const float4*)(wp);
        float4 wb = *(const float4*)(wp + 4);
        a += bf16_f32((unsigned short)h8[0]) * wa.x;
        a += bf16_f32((unsigned short)h8[1]) * wa.y;
        a += bf16_f32((unsigned short)h8[2]) * wa.z;
        a += bf16_f32((unsigned short)h8[3]) * wa.w;
        a += bf16_f32((unsigned short)h8[4]) * wb.x;
        a += bf16_f32((unsigned short)h8[5]) * wb.y;
        a += bf16_f32((unsigned short)h8[6]) * wb.z;
        a += bf16_f32((unsigned short)h8[7]) * wb.w;
    }
    a += __shfl_xor(a, 1);
    a += __shfl_xor(a, 2);
    a += __shfl_xor(a, 4);
    if (kz == 0)
        logits[((size_t)(b0 + lb) * SEQ + tprev) * VOCAB + w * NVW + v2] = a + bo;
}

// ---------------- persistent recurrence kernel ----------------
// grid = 64 blocks (4 groups x 16 col-slices of 64), 1024 threads (16 waves), 112KB LDS.
// waves: wv = ks(4) x ct(4): ct = column-tile (16 cols), ks = k-slice (256 k).
// W_hh slice held in VGPRs: whi[8]+wlo[8] short8 = 64 VGPR/thread.
extern "C" __global__ void __launch_bounds__(NTHR, 4)
rnn_kernel(const int* __restrict__ x, const float* __restrict__ h0,
           const float* __restrict__ W_hh,
           const float* __restrict__ E2, const float* __restrict__ WoT,
           const float* __restrict__ b_out,
           float* __restrict__ hp, int* __restrict__ flags,
           float* __restrict__ logits, float* __restrict__ hf) {
    extern __shared__ char lds_raw[];
    short* sHi   = (short*)lds_raw;                  // [16][1024] bf16 hi, chunk-swizzled: 32KB
    short* sLo   = (short*)(lds_raw + 32768);        // 32KB
    float* sPart = (float*)(lds_raw + 65536);        // [4][16][64] f32: 16KB
    int*   sX    = (int*)(lds_raw + 81920);          // [16][512] int: 32KB

    const int bid = blockIdx.x;
    const int g  = bid & 3;
    const int w  = bid >> 2;
    const int b0 = g * BG;
    const int j0 = w * CJ;
    const int tid  = threadIdx.x;
    const int lane = tid & 63;
    const int wv   = tid >> 6;
    const int ct   = wv & 3;
    const int ks   = wv >> 2;
    const int ar   = lane & 15;       // A row (batch) in frag / C col
    const int acg  = lane >> 4;       // k-subgroup / C row-group

    // ---- prologue: x slice -> LDS ----
    {
        const int4* xs4 = (const int4*)(x + (size_t)b0 * SEQ);
        ((int4*)sX)[tid]        = xs4[tid];
        ((int4*)sX)[tid + 1024] = xs4[tid + 1024];
    }

    // ---- prologue: W_hh slice -> bf16 hi/lo VGPR fragments ----
    // wave (ct,ks): B[k = ks*256 + kc*32 + acg*8 + e][col = j0 + ct*16 + ar]
    short8_t whi[8], wlo[8];
    {
        const int col = j0 + ct * 16 + ar;
#pragma unroll
        for (int kc = 0; kc < 8; ++kc) {
            int kb = ks * 256 + kc * 32 + acg * 8;
#pragma unroll
            for (int e = 0; e < 8; ++e) {
                float wval = W_hh[(size_t)(kb + e) * HIDDEN + col];
                unsigned short hi = bf16_rne(wval);
                whi[kc][e] = (short)hi;
                wlo[kc][e] = (short)bf16_rne(wval - bf16_f32(hi));
            }
        }
    }

    // logits / finish thread maps
    const int lb = tid >> 6;                 // batch row (== wv)
    const int v2 = (tid >> 3) & 7;           // vocab row within slice
    const int kz = tid & 7;                  // k-partition
    const float bo = b_out[w * NVW + v2];
    const float* wrowBase = WoT + (size_t)(w * NVW + v2) * HIDDEN;
    const int fb = tid >> 6, fj = tid & 63;  // finish: batch, col

    __syncthreads();

    for (int t = 0; t < SEQ; ++t) {
        if (t > 0) {
            if (tid < 64) group_poll(flags, g, lane, t);
            __syncthreads();
        }

        // ---- stage h_t (f32, MALL-coherent) -> bf16 hi/lo in LDS ----
        // thread: row fb, chunks c0=fj, c1=64+fj (chunk c stored at c^(row&7))
        {
            const float* src = (t == 0) ? (h0 + (size_t)b0 * HIDDEN)
                                        : (hp + (size_t)((t - 1) & 1) * BATCH * HIDDEN
                                              + (size_t)b0 * HIDDEN);
            const float* q0 = src + (size_t)fb * HIDDEN + fj * 8;
            const float* q1 = q0 + 512;
            float4 fa0 = cload4(q0);
            float4 fa1 = cload4(q0 + 4);
            float4 fb0 = cload4(q1);
            float4 fb1 = cload4(q1 + 4);
            WAITVM0();
            __builtin_amdgcn_sched_barrier(0);
            int rx = fb & 7;
            short8_t h8, l8;
            split8(fa0, fa1, &h8, &l8);
            int cs0 = (fj ^ rx) << 3;
            *(short8_t*)(sHi + fb * 1024 + cs0) = h8;
            *(short8_t*)(sLo + fb * 1024 + cs0) = l8;
            split8(fb0, fb1, &h8, &l8);
            int cs1 = ((64 + fj) ^ rx) << 3;
            *(short8_t*)(sHi + fb * 1024 + cs1) = h8;
            *(short8_t*)(sLo + fb * 1024 + cs1) = l8;
        }
        // e2 prefetch (overlaps barrier + MFMA)
        const float e2 = E2[(size_t)sX[fb * SEQ + t] * HIDDEN + j0 + fj];
        __syncthreads();   // (a)

        // ---- MFMA: C[16b x 16j(ct)] over 256-k slice ks ----
        f32x4 acc0 = {0.f, 0.f, 0.f, 0.f};
        f32x4 acc1 = {0.f, 0.f, 0.f, 0.f};
#pragma unroll
        for (int kc = 0; kc < 8; ++kc) {
            int c8 = ks * 32 + kc * 4 + acg;
            int off = ar * 1024 + ((c8 ^ (ar & 7)) << 3);
            short8_t ahi = *(const short8_t*)(sHi + off);
            short8_t alo = *(const short8_t*)(sLo + off);
            if (kc & 1) {
                acc1 = __builtin_amdgcn_mfma_f32_16x16x32_bf16(ahi, whi[kc], acc1, 0, 0, 0);
                acc1 = __builtin_amdgcn_mfma_f32_16x16x32_bf16(alo, whi[kc], acc1, 0, 0, 0);
                acc1 = __builtin_amdgcn_mfma_f32_16x16x32_bf16(ahi, wlo[kc], acc1, 0, 0, 0);
            } else {
                acc0 = __builtin_amdgcn_mfma_f32_16x16x32_bf16(ahi, whi[kc], acc0, 0, 0, 0);
                acc0 = __builtin_amdgcn_mfma_f32_16x16x32_bf16(alo, whi[kc], acc0, 0, 0, 0);
                acc0 = __builtin_amdgcn_mfma_f32_16x16x32_bf16(ahi, wlo[kc], acc0, 0, 0, 0);
            }
        }
        // write partials: sPart[ks][b=acg*4+q][j=ct*16+ar]
#pragma unroll
        for (int q = 0; q < 4; ++q)
            sPart[ks * 1024 + (acg * 4 + q) * 64 + ct * 16 + ar] = acc0[q] + acc1[q];
        __syncthreads();   // (b)

        // ---- finish: all 1024 threads, one output each ----
        {
            float s = sPart[fb * 64 + fj] + sPart[1024 + fb * 64 + fj]
                    + sPart[2048 + fb * 64 + fj] + sPart[3072 + fb * 64 + fj];
            float hn = tanhf(s + e2);
            float* hpo = hp + (size_t)(t & 1) * BATCH * HIDDEN;
            cstoref(hpo + (size_t)(b0 + fb) * HIDDEN + j0 + fj, hn);
            if (t == SEQ - 1)
                hf[(size_t)(b0 + fb) * HIDDEN + j0 + fj] = hn;
        }
        WAITVM0();
        __syncthreads();   // (c): all h stores acked
        if (tid == 0)
            cstorei(flags + (((size_t)g * 16 + w) << 4), t + 1);

        // ---- fused logits for position t-1 (overlaps peers' next step) ----
        if (t > 0)
            logits_phase(sHi, wrowBase, bo, logits, b0, w, t - 1, lb, v2, kz);
    }

    // ---- epilogue: logits for position SEQ-1 from h_SEQ ----
    if (tid < 64) group_poll(flags, g, lane, SEQ);
    __syncthreads();
    {
        const float* src = hp + (size_t)((SEQ - 1) & 1) * BATCH * HIDDEN + (size_t)b0 * HIDDEN;
        const float* q0 = src + (size_t)fb * HIDDEN + fj * 8;
        const float* q1 = q0 + 512;
        float4 fa0 = cload4(q0);
        float4 fa1 = cload4(q0 + 4);
        float4 fb0 = cload4(q1);
        float4 fb1 = cload4(q1 + 4);
        WAITVM0();
        __builtin_amdgcn_sched_barrier(0);
        int rx = fb & 7;
        short8_t h8, l8;
        split8(fa0, fa1, &h8, &l8);
        int cs0 = (fj ^ rx) << 3;
        *(short8_t*)(sHi + fb * 1024 + cs0) = h8;
        *(short8_t*)(sLo + fb * 1024 + cs0) = l8;
        split8(fb0, fb1, &h8, &l8);
        int cs1 = ((64 + fj) ^ rx) << 3;
        *(short8_t*)(sHi + fb * 1024 + cs1) = h8;
        *(short8_t*)(sLo + fb * 1024 + cs1) = l8;
    }
    __syncthreads();
    logits_phase(sHi, wrowBase, bo, logits, b0, w, SEQ - 1, lb, v2, kz);
}

extern "C" void kernel_launch(void* const* d_in, const int* in_sizes, int n_in,
                              void* d_out, int out_size, void* d_ws, size_t ws_size,
                              hipStream_t stream) {
    (void)in_sizes; (void)n_in; (void)out_size; (void)ws_size;
    const int*   x     = (const int*)  d_in[0];
    const float* h0    = (const float*)d_in[1];
    const float* emb   = (const float*)d_in[2];
    const float* W_hx  = (const float*)d_in[3];
    const float* b_hx  = (const float*)d_in[4];
    const float* W_hh  = (const float*)d_in[5];
    const float* W_out = (const float*)d_in[6];
    const float* b_out = (const float*)d_in[7];

    float* logits = (float*)d_out;
    float* hf     = logits + (size_t)BATCH * SEQ * VOCAB;

    float* ws  = (float*)d_ws;
    float* E2  = ws + E2_OFF;
    float* WoT = ws + WOT_OFF;
    float* hp  = ws + HP_OFF;
    int*   flags = (int*)(ws + FLG_OFF);

    hipMemsetAsync(flags, 0, NGROUP * 16 * 64, stream);
    e2_kernel<<<512, 256, 0, stream>>>(emb, W_hx, b_hx, E2);
    wot_kernel<<<128, 256, 0, stream>>>(W_out, WoT);

    hipFuncSetAttribute(reinterpret_cast<const void*>(rnn_kernel),
                        hipFuncAttributeMaxDynamicSharedMemorySize, 114688);
    rnn_kernel<<<NGROUP * NWG, NTHR, 114688, stream>>>(x, h0, W_hh, E2, WoT, b_out,
                                                       hp, flags, logits, hf);
}

// Round 6
// 1706.905 us; speedup vs baseline: 5.5415x; 2.3004x over previous
//
#include <hip/hip_runtime.h>
#include <stdint.h>
#include <stddef.h>

#define VOCAB  128
#define HIDDEN 1024
#define BATCH  64
#define SEQ    512

#define NGROUP 4      // batch groups
#define BG     16     // batches per group
#define NWG    32     // workgroups per group (column slices)
#define CJ     32     // W_hh columns per WG
#define NVW    4      // vocab rows per WG (VOCAB/NWG)
#define NTHR   512

// ws layout in float units
#define E2_OFF   0          // [128][1024] f32
#define WOT_OFF  131072     // [128][1024] f32
#define HPH_OFF  262144     // [2][64][1024] bf16 hi
#define HPL_OFF  327680     // [2][64][1024] bf16 lo
#define FLG_OFF  393216     // int flags[NGROUP][32], stride 16 ints

typedef __attribute__((ext_vector_type(8))) short short8_t;
typedef __attribute__((ext_vector_type(4))) float f32x4;

// ---------------- coherent (cross-XCD, MALL-level) access helpers ----------------
__device__ __forceinline__ uint4 cload4u(const void* p) {
    uint4 v;
    asm volatile("global_load_dwordx4 %0, %1, off sc0 sc1" : "=v"(v) : "v"(p));
    return v;
}
__device__ __forceinline__ int cloadi(const int* p) {
    int v;
    asm volatile("global_load_dword %0, %1, off sc0 sc1\n\ts_waitcnt vmcnt(0)"
                 : "=v"(v) : "v"(p) : "memory");
    return v;
}
__device__ __forceinline__ void cstore_short(void* p, unsigned int x) {
    asm volatile("global_store_short %0, %1, off sc0 sc1" :: "v"(p), "v"(x) : "memory");
}
__device__ __forceinline__ void cstorei(int* p, int x) {
    asm volatile("global_store_dword %0, %1, off sc0 sc1" :: "v"(p), "v"(x) : "memory");
}
#define WAITVM0() asm volatile("s_waitcnt vmcnt(0)" ::: "memory")

// ---------------- bf16 split helpers ----------------
__device__ __forceinline__ unsigned short bf16_rne(float f) {
    unsigned int u = __float_as_uint(f);
    u += 0x7FFF + ((u >> 16) & 1);
    return (unsigned short)(u >> 16);
}
__device__ __forceinline__ float bf16_f32(unsigned short h) {
    return __uint_as_float(((unsigned int)h) << 16);
}

// ---------------- E2 = emb @ W_hx + b_hx  ([128][1024]) ----------------
__global__ void e2_kernel(const float* __restrict__ emb, const float* __restrict__ W_hx,
                          const float* __restrict__ b_hx, float* __restrict__ E2) {
    int v = blockIdx.x >> 2;
    int j = (blockIdx.x & 3) * 256 + threadIdx.x;
    const float* er = emb + (size_t)v * HIDDEN;
    float acc = 0.f;
#pragma unroll 8
    for (int k = 0; k < HIDDEN; ++k)
        acc += er[k] * W_hx[(size_t)k * HIDDEN + j];
    E2[(size_t)v * HIDDEN + j] = acc + b_hx[j];
}

// ---------------- WoT[v][k] = W_out[k][v] ----------------
__global__ void wot_kernel(const float* __restrict__ W_out, float* __restrict__ WoT) {
    int v  = blockIdx.x;
    int k4 = threadIdx.x;
    float4 r;
    r.x = W_out[(size_t)(k4*4+0)*VOCAB + v];
    r.y = W_out[(size_t)(k4*4+1)*VOCAB + v];
    r.z = W_out[(size_t)(k4*4+2)*VOCAB + v];
    r.w = W_out[(size_t)(k4*4+3)*VOCAB + v];
    ((float4*)(WoT + (size_t)v * HIDDEN))[k4] = r;
}

// ---------------- persistent recurrence kernel ----------------
// grid = 128 blocks (4 groups x 32 col-slices), 512 threads (8 waves), 112KB LDS.
// LDS: sHi[16][1024] bf16 (chunk-swizzled), sLo same, sPart[8][512] f32, sX[16][512] int.
extern "C" __global__ void __launch_bounds__(NTHR, 2)
rnn_kernel(const int* __restrict__ x, const float* __restrict__ h0,
           const float* __restrict__ W_hh,
           const float* __restrict__ E2, const float* __restrict__ WoT,
           const float* __restrict__ b_out,
           unsigned short* __restrict__ hpHi, unsigned short* __restrict__ hpLo,
           int* __restrict__ flags,
           float* __restrict__ logits, float* __restrict__ hf) {
    extern __shared__ char lds_raw[];
    short* sHi  = (short*)lds_raw;                    // 16*1024 bf16 = 32KB
    short* sLo  = sHi + 16 * 1024;                    // 32KB
    float* sPart = (float*)(sLo + 16 * 1024);         // 8*512 f32 = 16KB (logits reuse: 8*64)
    int*   sX   = (int*)(sPart + 8 * 512);            // 16*512 int = 32KB

    const int wg = blockIdx.x;
    const int g  = wg / NWG;
    const int w  = wg % NWG;
    const int b0 = g * BG;
    const int j0 = w * CJ;
    const int tid  = threadIdx.x;
    const int lane = tid & 63;
    const int wv   = tid >> 6;
    int* flg = flags + (((size_t)g) << 9);            // stride 16 ints per flag

    // ---- prologue: x slice -> LDS ----
    {
        const int4* xs4 = (const int4*)(x + (size_t)b0 * SEQ);
#pragma unroll
        for (int i = 0; i < 4; ++i)
            ((int4*)sX)[tid + 512 * i] = xs4[tid + 512 * i];
    }

    // ---- prologue: W_hh column slice -> bf16 hi/lo fragments in VGPRs ----
    // wave wv owns k in [wv*128, wv*128+128); B-frag: lane l holds B[k=(l>>4)*8+e][col=l&15]
    short8_t whi[2][4], wlo[2][4];
    {
        const int colb = lane & 15, kgrp = lane >> 4;
#pragma unroll
        for (int ct = 0; ct < 2; ++ct) {
            int col = j0 + ct * 16 + colb;
#pragma unroll
            for (int c = 0; c < 4; ++c) {
                int kb = wv * 128 + c * 32 + kgrp * 8;
#pragma unroll
                for (int e = 0; e < 8; ++e) {
                    float wval = W_hh[(size_t)(kb + e) * HIDDEN + col];
                    unsigned short hi = bf16_rne(wval);
                    whi[ct][c][e] = (short)hi;
                    wlo[ct][c][e] = (short)bf16_rne(wval - bf16_f32(hi));
                }
            }
        }
    }

    // ---- prologue: W_out slice (NVW=4 vocab rows) -> bf16-hi B-frags (cols 4..15 zero) ----
    short8_t wvo[4];
    {
        const int colv = lane & 15, kgrp = lane >> 4;
#pragma unroll
        for (int c = 0; c < 4; ++c) {
            int kb = wv * 128 + c * 32 + kgrp * 8;
#pragma unroll
            for (int e = 0; e < 8; ++e) {
                float wval = (colv < NVW) ? WoT[(size_t)(w * NVW + colv) * HIDDEN + kb + e] : 0.f;
                wvo[c][e] = (short)bf16_rne(wval);
            }
        }
    }
    const float boV = (tid < 64) ? b_out[w * NVW + (tid & 3)] : 0.f;
    __syncthreads();

    const int srow = tid >> 5;                  // staging row [0,16)
    const int sslt = tid & 31;                  // staging chunk slot
    const int rb = tid >> 5, jb = tid & 31;     // reduce mapping: batch, col
    const int ar = lane & 15, acg = lane >> 4;  // A-frag row / k-group

    for (int t = 0; t < SEQ; ++t) {
        // ---- inter-WG barrier: all of group's flags >= t ----
        if (t > 0) {
            if (tid < 64) {
                int guard = 0;
                while (guard < (1 << 24)) {
                    int v = cloadi(flg + ((lane & 31) << 4));
                    if (__all(v >= t)) break;
                    __builtin_amdgcn_s_sleep(1);
                    ++guard;
                }
            }
            __syncthreads();
        }

        // ---- stage h_t (bf16 hi/lo) into LDS; 16B chunk c stored at c^(row&7) ----
        float e2p;
        if (t == 0) {
#pragma unroll
            for (int i = 0; i < 4; ++i) {
                int c = i * 32 + sslt;
                const float* p = h0 + (size_t)(b0 + srow) * HIDDEN + c * 8;
                short8_t h8, l8;
#pragma unroll
                for (int e = 0; e < 8; ++e) {
                    float vv = p[e];
                    unsigned short hi = bf16_rne(vv);
                    h8[e] = (short)hi;
                    l8[e] = (short)bf16_rne(vv - bf16_f32(hi));
                }
                int cs = (c ^ (srow & 7)) << 3;
                *(short8_t*)(sHi + srow * 1024 + cs) = h8;
                *(short8_t*)(sLo + srow * 1024 + cs) = l8;
            }
            e2p = E2[(size_t)sX[rb * SEQ + t] * HIDDEN + j0 + jb];
        } else {
            const unsigned short* srcH = hpHi + (size_t)((t - 1) & 1) * BATCH * HIDDEN
                                              + (size_t)(b0 + srow) * HIDDEN;
            const unsigned short* srcL = hpLo + (size_t)((t - 1) & 1) * BATCH * HIDDEN
                                              + (size_t)(b0 + srow) * HIDDEN;
            uint4 th[4], tl[4];
#pragma unroll
            for (int i = 0; i < 4; ++i) {
                int c = i * 32 + sslt;
                th[i] = cload4u(srcH + c * 8);
                tl[i] = cload4u(srcL + c * 8);
            }
            e2p = E2[(size_t)sX[rb * SEQ + t] * HIDDEN + j0 + jb];   // prefetch under MALL latency
            WAITVM0();
            __builtin_amdgcn_sched_barrier(0);
#pragma unroll
            for (int i = 0; i < 4; ++i) {
                int c = i * 32 + sslt;
                int cs = (c ^ (srow & 7)) << 3;
                *(uint4*)(sHi + srow * 1024 + cs) = th[i];
                *(uint4*)(sLo + srow * 1024 + cs) = tl[i];
            }
        }
        __syncthreads();   // (a)

        // ---- MFMA phase: C[16b x 32j] += h[16 x 128k] * W[128k x 32j] per wave ----
        f32x4 acc0 = {0.f, 0.f, 0.f, 0.f};
        f32x4 acc1 = {0.f, 0.f, 0.f, 0.f};
#pragma unroll
        for (int c = 0; c < 4; ++c) {
            int c8 = wv * 16 + c * 4 + acg;          // logical 16B chunk of row ar
            int off = ar * 1024 + ((c8 ^ (ar & 7)) << 3);
            short8_t ahi = *(const short8_t*)(sHi + off);
            short8_t alo = *(const short8_t*)(sLo + off);
            acc0 = __builtin_amdgcn_mfma_f32_16x16x32_bf16(ahi, whi[0][c], acc0, 0, 0, 0);
            acc1 = __builtin_amdgcn_mfma_f32_16x16x32_bf16(ahi, whi[1][c], acc1, 0, 0, 0);
            acc0 = __builtin_amdgcn_mfma_f32_16x16x32_bf16(alo, whi[0][c], acc0, 0, 0, 0);
            acc1 = __builtin_amdgcn_mfma_f32_16x16x32_bf16(alo, whi[1][c], acc1, 0, 0, 0);
            acc0 = __builtin_amdgcn_mfma_f32_16x16x32_bf16(ahi, wlo[0][c], acc0, 0, 0, 0);
            acc1 = __builtin_amdgcn_mfma_f32_16x16x32_bf16(ahi, wlo[1][c], acc1, 0, 0, 0);
        }
        // C layout: col=lane&15, row=(lane>>4)*4+q  -> sPart[wv][row][col(+16*ct)]
#pragma unroll
        for (int q = 0; q < 4; ++q) {
            sPart[wv * 512 + (acg * 4 + q) * 32 + ar]      = acc0[q];
            sPart[wv * 512 + (acg * 4 + q) * 32 + 16 + ar] = acc1[q];
        }
        __syncthreads();   // (b)

        // ---- reduce 8 wave-partials + E2 + tanh; coherent bf16 hi/lo store ----
        {
            float s = 0.f;
#pragma unroll
            for (int z = 0; z < 8; ++z) s += sPart[z * 512 + tid];
            float hn = tanhf(s + e2p);
            unsigned short hi = bf16_rne(hn);
            unsigned short lo = bf16_rne(hn - bf16_f32(hi));
            size_t di = (size_t)(t & 1) * BATCH * HIDDEN + (size_t)(b0 + rb) * HIDDEN + j0 + jb;
            cstore_short(hpHi + di, hi);
            cstore_short(hpLo + di, lo);
            if (t == SEQ - 1)
                hf[(size_t)(b0 + rb) * HIDDEN + j0 + jb] = hn;
        }
        WAITVM0();
        __syncthreads();   // (c): all h stores acked
        if (tid == 0)
            cstorei(flg + (w << 4), t + 1);

        // ---- fused logits for position t-1 via MFMA (B = 4 vocab cols, 12 padded) ----
        if (t > 0) {
            f32x4 accL = {0.f, 0.f, 0.f, 0.f};
#pragma unroll
            for (int c = 0; c < 4; ++c) {
                int c8 = wv * 16 + c * 4 + acg;
                int off = ar * 1024 + ((c8 ^ (ar & 7)) << 3);
                short8_t ahi = *(const short8_t*)(sHi + off);
                accL = __builtin_amdgcn_mfma_f32_16x16x32_bf16(ahi, wvo[c], accL, 0, 0, 0);
            }
            if (ar < NVW) {
#pragma unroll
                for (int q = 0; q < 4; ++q)
                    sPart[wv * 64 + (acg * 4 + q) * 4 + ar] = accL[q];
            }
            __syncthreads();   // (d)
            if (tid < 64) {
                int b = tid >> 2, v = tid & 3;
                float s = 0.f;
#pragma unroll
                for (int z = 0; z < 8; ++z) s += sPart[z * 64 + b * 4 + v];
                logits[((size_t)(b0 + b) * SEQ + (t - 1)) * VOCAB + w * NVW + v] = s + boV;
            }
        }
    }

    // ---- epilogue: logits for position SEQ-1 from h_SEQ ----
    if (tid < 64) {
        int guard = 0;
        while (guard < (1 << 24)) {
            int v = cloadi(flg + ((lane & 31) << 4));
            if (__all(v >= SEQ)) break;
            __builtin_amdgcn_s_sleep(1);
            ++guard;
        }
    }
    __syncthreads();
    {
        const unsigned short* srcH = hpHi + (size_t)((SEQ - 1) & 1) * BATCH * HIDDEN
                                          + (size_t)(b0 + srow) * HIDDEN;
#pragma unroll
        for (int i = 0; i < 4; ++i) {
            int c = i * 32 + sslt;
            uint4 th = cload4u(srcH + c * 8);
            WAITVM0();
            int cs = (c ^ (srow & 7)) << 3;
            *(uint4*)(sHi + srow * 1024 + cs) = th;
        }
    }
    __syncthreads();
    {
        f32x4 accL = {0.f, 0.f, 0.f, 0.f};
#pragma unroll
        for (int c = 0; c < 4; ++c) {
            int c8 = wv * 16 + c * 4 + acg;
            int off = ar * 1024 + ((c8 ^ (ar & 7)) << 3);
            short8_t ahi = *(const short8_t*)(sHi + off);
            accL = __builtin_amdgcn_mfma_f32_16x16x32_bf16(ahi, wvo[c], accL, 0, 0, 0);
        }
        if (ar < NVW) {
#pragma unroll
            for (int q = 0; q < 4; ++q)
                sPart[wv * 64 + (acg * 4 + q) * 4 + ar] = accL[q];
        }
        __syncthreads();
        if (tid < 64) {
            int b = tid >> 2, v = tid & 3;
            float s = 0.f;
#pragma unroll
            for (int z = 0; z < 8; ++z) s += sPart[z * 64 + b * 4 + v];
            logits[((size_t)(b0 + b) * SEQ + (SEQ - 1)) * VOCAB + w * NVW + v] = s + boV;
        }
    }
}

extern "C" void kernel_launch(void* const* d_in, const int* in_sizes, int n_in,
                              void* d_out, int out_size, void* d_ws, size_t ws_size,
                              hipStream_t stream) {
    (void)in_sizes; (void)n_in; (void)out_size; (void)ws_size;
    const int*   x     = (const int*)  d_in[0];
    const float* h0    = (const float*)d_in[1];
    const float* emb   = (const float*)d_in[2];
    const float* W_hx  = (const float*)d_in[3];
    const float* b_hx  = (const float*)d_in[4];
    const float* W_hh  = (const float*)d_in[5];
    const float* W_out = (const float*)d_in[6];
    const float* b_out = (const float*)d_in[7];

    float* logits = (float*)d_out;
    float* hf     = logits + (size_t)BATCH * SEQ * VOCAB;

    float* ws  = (float*)d_ws;
    float* E2  = ws + E2_OFF;
    float* WoT = ws + WOT_OFF;
    unsigned short* hpHi = (unsigned short*)(ws + HPH_OFF);
    unsigned short* hpLo = (unsigned short*)(ws + HPL_OFF);
    int*   flags = (int*)(ws + FLG_OFF);

    hipMemsetAsync(flags, 0, NGROUP * 32 * 64, stream);
    e2_kernel<<<512, 256, 0, stream>>>(emb, W_hx, b_hx, E2);
    wot_kernel<<<128, 256, 0, stream>>>(W_out, WoT);

    hipFuncSetAttribute(reinterpret_cast<const void*>(rnn_kernel),
                        hipFuncAttributeMaxDynamicSharedMemorySize, 114688);
    rnn_kernel<<<NGROUP * NWG, NTHR, 114688, stream>>>(x, h0, W_hh, E2, WoT, b_out,
                                                       hpHi, hpLo, flags, logits, hf);
}

// Round 8
// 1652.792 us; speedup vs baseline: 5.7229x; 1.0327x over previous
//
#include <hip/hip_runtime.h>
#include <stdint.h>
#include <stddef.h>

#define VOCAB  128
#define HIDDEN 1024
#define BATCH  64
#define SEQ    512

#define NGROUP 4      // batch groups
#define BG     16     // batches per group
#define NWG    32     // workgroups per group (column slices)
#define CJ     32     // W_hh columns per WG
#define NVW    4      // vocab rows per WG (VOCAB/NWG)
#define NTHR   512

#define POISON 0x7F800000u   // (inf<<16): impossible for packed (bf16hi(tanh)<<16)|lo

// ws layout in float units
#define E2_OFF   0          // [128][1024] f32                    (131072 f)
#define WOT_OFF  131072     // [128][1024] bf16                   (65536 f)
#define BUF_OFF  196608     // [4][64][1024] u32 packed h         (262144 f)
// total 458752 floats = 1.75 MB

typedef __attribute__((ext_vector_type(8))) short short8_t;
typedef __attribute__((ext_vector_type(4))) float f32x4;

// ---------------- coherent (cross-XCD, MALL-level) access helpers ----------------
__device__ __forceinline__ uint4 cload4u(const void* p) {
    uint4 v;
    asm volatile("global_load_dwordx4 %0, %1, off sc0 sc1" : "=v"(v) : "v"(p));
    return v;
}
__device__ __forceinline__ void cstoreu(unsigned int* p, unsigned int x) {
    asm volatile("global_store_dword %0, %1, off sc0 sc1" :: "v"(p), "v"(x) : "memory");
}
// rule-18 discipline: every WAITVM0 that orders inline-asm load RESULTS against
// register-only consumer code must be followed by sched_barrier(0).
#define WAITVM0() asm volatile("s_waitcnt vmcnt(0)" ::: "memory")
#define SCHED_FENCE() __builtin_amdgcn_sched_barrier(0)

// ---------------- bf16 split helpers ----------------
__device__ __forceinline__ unsigned short bf16_rne(float f) {
    unsigned int u = __float_as_uint(f);
    u += 0x7FFF + ((u >> 16) & 1);
    return (unsigned short)(u >> 16);
}
__device__ __forceinline__ float bf16_f32(unsigned short h) {
    return __uint_as_float(((unsigned int)h) << 16);
}

// ---------------- E2 = emb @ W_hx + b_hx  ([128][1024] f32) ----------------
__global__ void e2_kernel(const float* __restrict__ emb, const float* __restrict__ W_hx,
                          const float* __restrict__ b_hx, float* __restrict__ E2) {
    int v = blockIdx.x >> 2;
    int j = (blockIdx.x & 3) * 256 + threadIdx.x;
    const float* er = emb + (size_t)v * HIDDEN;
    float acc = 0.f;
#pragma unroll 8
    for (int k = 0; k < HIDDEN; ++k)
        acc += er[k] * W_hx[(size_t)k * HIDDEN + j];
    E2[(size_t)v * HIDDEN + j] = acc + b_hx[j];
}

// ---------------- WoT[v][k] = bf16(W_out[k][v]) ----------------
__global__ void wot_kernel(const float* __restrict__ W_out, unsigned short* __restrict__ WoT) {
    int v  = blockIdx.x;
    int k4 = threadIdx.x;          // 256 threads * 4 k
    ushort4 r;
    r.x = bf16_rne(W_out[(size_t)(k4*4+0)*VOCAB + v]);
    r.y = bf16_rne(W_out[(size_t)(k4*4+1)*VOCAB + v]);
    r.z = bf16_rne(W_out[(size_t)(k4*4+2)*VOCAB + v]);
    r.w = bf16_rne(W_out[(size_t)(k4*4+3)*VOCAB + v]);
    ((ushort4*)(WoT + (size_t)v * HIDDEN))[k4] = r;
}

// ---------------- poison init (graph-replay deterministic) ----------------
__global__ void poison_kernel(unsigned int* __restrict__ bufs) {
    int i = blockIdx.x * 256 + threadIdx.x;    // 65536 uint4 = 4*64*1024 u32
    ((uint4*)bufs)[i] = make_uint4(POISON, POISON, POISON, POISON);
}

// ---------------- persistent recurrence kernel ----------------
// grid = 128 blocks (4 groups x 32 col-slices), 512 threads (8 waves), 112KB LDS.
// Exchange protocol: packed u32 h elements, poll-on-data with poison sentinel,
// 4 rotating buffers (data -> buf[t&3], poison -> buf[(t+2)&3], no flags).
extern "C" __global__ void __launch_bounds__(NTHR, 2)
rnn_kernel(const int* __restrict__ x, const float* __restrict__ h0,
           const float* __restrict__ W_hh,
           const float* __restrict__ E2, const unsigned short* __restrict__ WoT,
           const float* __restrict__ b_out,
           unsigned int* __restrict__ bufs,
           float* __restrict__ logits, float* __restrict__ hf) {
    extern __shared__ char lds_raw[];
    short* sHi  = (short*)lds_raw;                    // [16][1024] bf16 hi, chunk-swizzled: 32KB
    short* sLo  = sHi + 16 * 1024;                    // 32KB
    float* sPart = (float*)(sLo + 16 * 1024);         // [8][512] f32: 16KB (logits reuse [8][64])
    int*   sX   = (int*)(sPart + 8 * 512);            // [16][512] int: 32KB

    const int wg = blockIdx.x;
    const int g  = wg / NWG;
    const int w  = wg % NWG;
    const int b0 = g * BG;
    const int j0 = w * CJ;
    const int tid  = threadIdx.x;
    const int lane = tid & 63;
    const int wv   = tid >> 6;

    // ---- prologue: x slice -> LDS ----
    {
        const int4* xs4 = (const int4*)(x + (size_t)b0 * SEQ);
#pragma unroll
        for (int i = 0; i < 4; ++i)
            ((int4*)sX)[tid + 512 * i] = xs4[tid + 512 * i];
    }

    // ---- prologue: W_hh column slice -> bf16 hi/lo fragments in VGPRs ----
    // wave wv owns k in [wv*128, wv*128+128); B-frag: lane l holds B[k=(l>>4)*8+e][col=l&15]
    short8_t whi[2][4], wlo[2][4];
    {
        const int colb = lane & 15, kgrp = lane >> 4;
#pragma unroll
        for (int ct = 0; ct < 2; ++ct) {
            int col = j0 + ct * 16 + colb;
#pragma unroll
            for (int c = 0; c < 4; ++c) {
                int kb = wv * 128 + c * 32 + kgrp * 8;
#pragma unroll
                for (int e = 0; e < 8; ++e) {
                    float wval = W_hh[(size_t)(kb + e) * HIDDEN + col];
                    unsigned short hi = bf16_rne(wval);
                    whi[ct][c][e] = (short)hi;
                    wlo[ct][c][e] = (short)bf16_rne(wval - bf16_f32(hi));
                }
            }
        }
    }

    // ---- prologue: W_out slice (NVW=4 vocab rows) -> bf16 B-frags (cols 4..15 zero) ----
    short8_t wvo[4];
    {
        const int colv = lane & 15, kgrp = lane >> 4;
#pragma unroll
        for (int c = 0; c < 4; ++c) {
            int kb = wv * 128 + c * 32 + kgrp * 8;
#pragma unroll
            for (int e = 0; e < 8; ++e)
                wvo[c][e] = (colv < NVW)
                    ? (short)WoT[(size_t)(w * NVW + colv) * HIDDEN + kb + e] : (short)0;
        }
    }
    const float boV = (tid < 64) ? b_out[w * NVW + (tid & 3)] : 0.f;
    __syncthreads();

    const int srow = tid >> 5;                  // staging row [0,16)
    const int sslt = tid & 31;                  // staging chunk slot
    const int rb = tid >> 5, jb = tid & 31;     // finish mapping: batch, col
    const int ar = lane & 15, acg = lane >> 4;  // A-frag row / k-group

    for (int t = 0; t < SEQ; ++t) {
        // ---- stage h_t into LDS (bf16 hi/lo, 16B chunk c stored at c^(row&7)) ----
        float e2p = E2[(size_t)sX[rb * SEQ + t] * HIDDEN + j0 + jb];
        if (t == 0) {
#pragma unroll
            for (int i = 0; i < 4; ++i) {
                int c = i * 32 + sslt;
                const float* p = h0 + (size_t)(b0 + srow) * HIDDEN + c * 8;
                short8_t h8, l8;
#pragma unroll
                for (int e = 0; e < 8; ++e) {
                    float vv = p[e];
                    unsigned short hi = bf16_rne(vv);
                    h8[e] = (short)hi;
                    l8[e] = (short)bf16_rne(vv - bf16_f32(hi));
                }
                int cs = (c ^ (srow & 7)) << 3;
                *(short8_t*)(sHi + srow * 1024 + cs) = h8;
                *(short8_t*)(sLo + srow * 1024 + cs) = l8;
            }
        } else {
            // ---- poll-on-data: h_t lives in buf[(t-1)&3], written by peers at iter t-1 ----
            const unsigned int* src = bufs + ((size_t)((t - 1) & 3) << 16)
                                           + ((size_t)(b0 + srow) << 10);
            uint4 d[8];
            unsigned pend = 0xF;
            int guard = 0;
            do {
#pragma unroll
                for (int i = 0; i < 4; ++i)
                    if (pend & (1u << i)) {
                        int c = i * 32 + sslt;
                        d[2*i]   = cload4u(src + c * 8);
                        d[2*i+1] = cload4u(src + c * 8 + 4);
                    }
                WAITVM0();
                SCHED_FENCE();   // rule 18: pin the register-only checks AFTER the vmcnt wait
#pragma unroll
                for (int i = 0; i < 4; ++i)
                    if (pend & (1u << i)) {
                        bool ok = d[2*i].x   != POISON && d[2*i].y   != POISON
                               && d[2*i].z   != POISON && d[2*i].w   != POISON
                               && d[2*i+1].x != POISON && d[2*i+1].y != POISON
                               && d[2*i+1].z != POISON && d[2*i+1].w != POISON;
                        if (ok) pend &= ~(1u << i);
                    }
                if (!pend) break;
                __builtin_amdgcn_s_sleep(1);
            } while (++guard < (1 << 20));
            SCHED_FENCE();       // pin the unpack below after the final wait as well
#pragma unroll
            for (int i = 0; i < 4; ++i) {
                int c = i * 32 + sslt;
                int cs = (c ^ (srow & 7)) << 3;
                short8_t h8, l8;
                h8[0]=(short)(d[2*i].x>>16);   l8[0]=(short)(d[2*i].x&0xFFFF);
                h8[1]=(short)(d[2*i].y>>16);   l8[1]=(short)(d[2*i].y&0xFFFF);
                h8[2]=(short)(d[2*i].z>>16);   l8[2]=(short)(d[2*i].z&0xFFFF);
                h8[3]=(short)(d[2*i].w>>16);   l8[3]=(short)(d[2*i].w&0xFFFF);
                h8[4]=(short)(d[2*i+1].x>>16); l8[4]=(short)(d[2*i+1].x&0xFFFF);
                h8[5]=(short)(d[2*i+1].y>>16); l8[5]=(short)(d[2*i+1].y&0xFFFF);
                h8[6]=(short)(d[2*i+1].z>>16); l8[6]=(short)(d[2*i+1].z&0xFFFF);
                h8[7]=(short)(d[2*i+1].w>>16); l8[7]=(short)(d[2*i+1].w&0xFFFF);
                *(short8_t*)(sHi + srow * 1024 + cs) = h8;
                *(short8_t*)(sLo + srow * 1024 + cs) = l8;
            }
        }
        __syncthreads();   // (a)

        // ---- MFMA phase: C[16b x 32j] += h[16 x 128k] * W[128k x 32j] per wave ----
        f32x4 acc0 = {0.f, 0.f, 0.f, 0.f};
        f32x4 acc1 = {0.f, 0.f, 0.f, 0.f};
#pragma unroll
        for (int c = 0; c < 4; ++c) {
            int c8 = wv * 16 + c * 4 + acg;          // logical 16B chunk of row ar
            int off = ar * 1024 + ((c8 ^ (ar & 7)) << 3);
            short8_t ahi = *(const short8_t*)(sHi + off);
            short8_t alo = *(const short8_t*)(sLo + off);
            acc0 = __builtin_amdgcn_mfma_f32_16x16x32_bf16(ahi, whi[0][c], acc0, 0, 0, 0);
            acc1 = __builtin_amdgcn_mfma_f32_16x16x32_bf16(ahi, whi[1][c], acc1, 0, 0, 0);
            acc0 = __builtin_amdgcn_mfma_f32_16x16x32_bf16(alo, whi[0][c], acc0, 0, 0, 0);
            acc1 = __builtin_amdgcn_mfma_f32_16x16x32_bf16(alo, whi[1][c], acc1, 0, 0, 0);
            acc0 = __builtin_amdgcn_mfma_f32_16x16x32_bf16(ahi, wlo[0][c], acc0, 0, 0, 0);
            acc1 = __builtin_amdgcn_mfma_f32_16x16x32_bf16(ahi, wlo[1][c], acc1, 0, 0, 0);
        }
        // C layout: col=lane&15, row=(lane>>4)*4+q  -> sPart[wv][row][col(+16*ct)]
#pragma unroll
        for (int q = 0; q < 4; ++q) {
            sPart[wv * 512 + (acg * 4 + q) * 32 + ar]      = acc0[q];
            sPart[wv * 512 + (acg * 4 + q) * 32 + 16 + ar] = acc1[q];
        }
        __syncthreads();   // (b)

        // ---- finish: reduce 8 partials + E2 + tanh; fire-and-forget packed store ----
        {
            float s = 0.f;
#pragma unroll
            for (int z = 0; z < 8; ++z) s += sPart[z * 512 + tid];
            float hn = tanhf(s + e2p);
            unsigned short hi = bf16_rne(hn);
            unsigned short lo = bf16_rne(hn - bf16_f32(hi));
            unsigned int pk = ((unsigned int)hi << 16) | (unsigned int)lo;
            size_t idx = ((size_t)(b0 + rb) << 10) + j0 + jb;
            cstoreu(bufs + ((size_t)(t & 3) << 16) + idx, pk);             // data
            cstoreu(bufs + ((size_t)((t + 2) & 3) << 16) + idx, POISON);   // re-arm future buf
            if (t == SEQ - 1)
                hf[(size_t)(b0 + rb) * HIDDEN + j0 + jb] = hn;
        }
        __syncthreads();   // (c): sPart reads done -> logits may overwrite

        // ---- fused logits for position t-1 via MFMA (B = 4 vocab cols, 12 padded) ----
        if (t > 0) {
            f32x4 accL = {0.f, 0.f, 0.f, 0.f};
#pragma unroll
            for (int c = 0; c < 4; ++c) {
                int c8 = wv * 16 + c * 4 + acg;
                int off = ar * 1024 + ((c8 ^ (ar & 7)) << 3);
                short8_t ahi = *(const short8_t*)(sHi + off);
                accL = __builtin_amdgcn_mfma_f32_16x16x32_bf16(ahi, wvo[c], accL, 0, 0, 0);
            }
            if (ar < NVW) {
#pragma unroll
                for (int q = 0; q < 4; ++q)
                    sPart[wv * 64 + (acg * 4 + q) * 4 + ar] = accL[q];
            }
            __syncthreads();   // (d)
            if (tid < 64) {
                int b = tid >> 2, v = tid & 3;
                float s = 0.f;
#pragma unroll
                for (int z = 0; z < 8; ++z) s += sPart[z * 64 + b * 4 + v];
                logits[((size_t)(b0 + b) * SEQ + (t - 1)) * VOCAB + w * NVW + v] = s + boV;
            }
        }
    }

    // ---- epilogue: logits for position SEQ-1 from h_SEQ (poll buf[(SEQ-1)&3], hi only) ----
    {
        const unsigned int* src = bufs + ((size_t)((SEQ - 1) & 3) << 16)
                                       + ((size_t)(b0 + srow) << 10);
        uint4 d[8];
        unsigned pend = 0xF;
        int guard = 0;
        do {
#pragma unroll
            for (int i = 0; i < 4; ++i)
                if (pend & (1u << i)) {
                    int c = i * 32 + sslt;
                    d[2*i]   = cload4u(src + c * 8);
                    d[2*i+1] = cload4u(src + c * 8 + 4);
                }
            WAITVM0();
            SCHED_FENCE();   // rule 18
#pragma unroll
            for (int i = 0; i < 4; ++i)
                if (pend & (1u << i)) {
                    bool ok = d[2*i].x   != POISON && d[2*i].y   != POISON
                           && d[2*i].z   != POISON && d[2*i].w   != POISON
                           && d[2*i+1].x != POISON && d[2*i+1].y != POISON
                           && d[2*i+1].z != POISON && d[2*i+1].w != POISON;
                    if (ok) pend &= ~(1u << i);
                }
            if (!pend) break;
            __builtin_amdgcn_s_sleep(1);
        } while (++guard < (1 << 20));
        SCHED_FENCE();
        __syncthreads();
#pragma unroll
        for (int i = 0; i < 4; ++i) {
            int c = i * 32 + sslt;
            int cs = (c ^ (srow & 7)) << 3;
            short8_t h8;
            h8[0]=(short)(d[2*i].x>>16);   h8[1]=(short)(d[2*i].y>>16);
            h8[2]=(short)(d[2*i].z>>16);   h8[3]=(short)(d[2*i].w>>16);
            h8[4]=(short)(d[2*i+1].x>>16); h8[5]=(short)(d[2*i+1].y>>16);
            h8[6]=(short)(d[2*i+1].z>>16); h8[7]=(short)(d[2*i+1].w>>16);
            *(short8_t*)(sHi + srow * 1024 + cs) = h8;
        }
    }
    __syncthreads();
    {
        f32x4 accL = {0.f, 0.f, 0.f, 0.f};
#pragma unroll
        for (int c = 0; c < 4; ++c) {
            int c8 = wv * 16 + c * 4 + acg;
            int off = ar * 1024 + ((c8 ^ (ar & 7)) << 3);
            short8_t ahi = *(const short8_t*)(sHi + off);
            accL = __builtin_amdgcn_mfma_f32_16x16x32_bf16(ahi, wvo[c], accL, 0, 0, 0);
        }
        if (ar < NVW) {
#pragma unroll
            for (int q = 0; q < 4; ++q)
                sPart[wv * 64 + (acg * 4 + q) * 4 + ar] = accL[q];
        }
        __syncthreads();
        if (tid < 64) {
            int b = tid >> 2, v = tid & 3;
            float s = 0.f;
#pragma unroll
            for (int z = 0; z < 8; ++z) s += sPart[z * 64 + b * 4 + v];
            logits[((size_t)(b0 + b) * SEQ + (SEQ - 1)) * VOCAB + w * NVW + v] = s + boV;
        }
    }
}

extern "C" void kernel_launch(void* const* d_in, const int* in_sizes, int n_in,
                              void* d_out, int out_size, void* d_ws, size_t ws_size,
                              hipStream_t stream) {
    (void)in_sizes; (void)n_in; (void)out_size; (void)ws_size;
    const int*   x     = (const int*)  d_in[0];
    const float* h0    = (const float*)d_in[1];
    const float* emb   = (const float*)d_in[2];
    const float* W_hx  = (const float*)d_in[3];
    const float* b_hx  = (const float*)d_in[4];
    const float* W_hh  = (const float*)d_in[5];
    const float* W_out = (const float*)d_in[6];
    const float* b_out = (const float*)d_in[7];

    float* logits = (float*)d_out;
    float* hf     = logits + (size_t)BATCH * SEQ * VOCAB;

    float* ws  = (float*)d_ws;
    float* E2  = ws + E2_OFF;
    unsigned short* WoT = (unsigned short*)(ws + WOT_OFF);
    unsigned int*   bufs = (unsigned int*)(ws + BUF_OFF);

    poison_kernel<<<256, 256, 0, stream>>>(bufs);
    e2_kernel<<<512, 256, 0, stream>>>(emb, W_hx, b_hx, E2);
    wot_kernel<<<128, 256, 0, stream>>>(W_out, WoT);

    hipFuncSetAttribute(reinterpret_cast<const void*>(rnn_kernel),
                        hipFuncAttributeMaxDynamicSharedMemorySize, 114688);
    rnn_kernel<<<NGROUP * NWG, NTHR, 114688, stream>>>(x, h0, W_hh, E2, WoT, b_out,
                                                       bufs, logits, hf);
}